// Round 2
// baseline (28.616 us; speedup 1.0000x reference)
//
#include <hip/hip_runtime.h>

// Soft decision forest, depth=4, W=4: B=256, T=64, N=341 nodes, 1024 leaves.
// Output[b,t,L] = prod_{l=0..4} softmax(in[b,t,n_l,:])[j_l],
// L = j0*256 + j1*64 + j2*16 + j3*4 + j4, preorder node indices:
// n0=0, n1=1+85*j0, n2=n1+1+21*j1, n3=n2+1+5*j2, n4=n3+1+j3.
//
// Wave-per-bt structure: each 64-lane wave owns one (b,t) pair with a private
// LDS region -> no __syncthreads(), 6 outstanding dwordx4 loads per lane.

#define NUM_NODES 341

__global__ __launch_bounds__(256) void forest_kernel(const float* __restrict__ in,
                                                     float* __restrict__ out) {
    // 4 waves/block, each with a private 341-node prob table (4*5456 B = 21824 B)
    __shared__ float4 sP[4][NUM_NODES];

    const int tid  = threadIdx.x;
    const int wave = tid >> 6;
    const int lane = tid & 63;
    const int bt   = blockIdx.x * 4 + wave;   // 0..16383

    float4* sPw = sP[wave];
    const float* sPf = reinterpret_cast<const float*>(sPw);

    // ---- Phase 1: load all 341 node rows (6 dwordx4 in flight), softmax ----
    const float4* in4 = reinterpret_cast<const float4*>(in) + (size_t)bt * NUM_NODES;
    float4 v[6];
#pragma unroll
    for (int i = 0; i < 5; ++i) v[i] = in4[lane + 64 * i];
    const bool tail = (lane < NUM_NODES - 320);  // 21 lanes
    if (tail) v[5] = in4[lane + 320];

#pragma unroll
    for (int i = 0; i < 6; ++i) {
        if (i < 5 || tail) {
            float4 x = v[i];
            float m  = fmaxf(fmaxf(x.x, x.y), fmaxf(x.z, x.w));
            float e0 = __expf(x.x - m);
            float e1 = __expf(x.y - m);
            float e2 = __expf(x.z - m);
            float e3 = __expf(x.w - m);
            float r  = 1.0f / (e0 + e1 + e2 + e3);
            sPw[lane + 64 * i] = make_float4(e0 * r, e1 * r, e2 * r, e3 * r);
        }
    }

    // Wave-local LDS visibility: all lanes' ds_writes must land before any
    // lane's ds_read of another lane's data. Same wave -> no s_barrier needed.
    asm volatile("s_waitcnt lgkmcnt(0)" ::: "memory");
    __builtin_amdgcn_sched_barrier(0);

    // ---- Phase 2: 4 iterations; iter = j0, lane encodes (j1,j2,j3), the
    // float4 components are j4. Stores are wave-contiguous 1 KB. ----
    const int j1 = lane >> 4;
    const int j2 = (lane >> 2) & 3;
    const int j3 = lane & 3;

    float4* out4 = reinterpret_cast<float4*>(out) + (size_t)bt * 256;

#pragma unroll
    for (int j0 = 0; j0 < 4; ++j0) {
        const int n1 = 1 + 85 * j0;           // wave-uniform
        const int n2 = n1 + 1 + 21 * j1;
        const int n3 = n2 + 1 + 5 * j2;
        const int n4 = n3 + 1 + j3;

        const float pre = sPf[j0]             // root, broadcast
                        * sPf[n1 * 4 + j1]
                        * sPf[n2 * 4 + j2]
                        * sPf[n3 * 4 + j3];

        float4 pv = sPw[n4];
        out4[j0 * 64 + lane] = make_float4(pre * pv.x, pre * pv.y,
                                           pre * pv.z, pre * pv.w);
    }
}

extern "C" void kernel_launch(void* const* d_in, const int* in_sizes, int n_in,
                              void* d_out, int out_size, void* d_ws, size_t ws_size,
                              hipStream_t stream) {
    const float* in = (const float*)d_in[0];
    float* out = (float*)d_out;
    const int num_blocks = (256 * 64) / 4;  // one bt per wave, 4 waves/block
    forest_kernel<<<num_blocks, 256, 0, stream>>>(in, out);
}